// Round 8
// baseline (216.140 us; speedup 1.0000x reference)
//
#include <hip/hip_runtime.h>
#include <math.h>

// Problem constants (compile-time fixed)
#define NB   2
#define LQ   13294
#define NROWS (NB*LQ)      // 26588
#define CDIM 256
#define HSLICES (NROWS + 1)                       // +1 zero pad slice per head
#define HS32 ((size_t)HSLICES * 32)               // u16 per head

typedef unsigned short u16;
typedef unsigned int   u32;
typedef short bf16x8 __attribute__((ext_vector_type(8)));
typedef float f32x4  __attribute__((ext_vector_type(4)));
typedef float f32x2  __attribute__((ext_vector_type(2)));

struct alignas(8) U16x4 { u16 x, y, z, w; };

__device__ __forceinline__ u16 f2bf(float f) {   // round-to-nearest-even
    u32 u = __builtin_bit_cast(u32, f);
    u += 0x7FFFu + ((u >> 16) & 1u);
    return (u16)(u >> 16);
}

__device__ __forceinline__ void gload_lds16(const void* g, void* l) {
    __builtin_amdgcn_global_load_lds(
        (__attribute__((address_space(1))) void*)g,
        (__attribute__((address_space(3))) void*)l, 16, 0, 0);
}

// unpack one u32 of 2 packed bf16 into f32x2 {lo, hi}
__device__ __forceinline__ f32x2 bfpair(u32 u) {
    union { u32 w[2]; f32x2 v; } x;
    x.w[0] = u << 16;
    x.w[1] = u & 0xFFFF0000u;
    return x.v;
}

// raw barrier with compiler memory fences (s_barrier alone is not a
// code-motion barrier for LLVM; empty asm pins loads/stores)
__device__ __forceinline__ void block_barrier() {
    asm volatile("" ::: "memory");
    __builtin_amdgcn_s_barrier();
    asm volatile("" ::: "memory");
}

// ONE prep dispatch: cvt query (blocks 0..6646), cvt inflat (6647..13293),
// weights concat [Wv|Woff|Wa|Wo] -> bf16 (13294..14189).
__global__ __launch_bounds__(256)
void prep_all(const float4* __restrict__ query, const float4* __restrict__ inflat,
              const float* __restrict__ Wv, const float* __restrict__ Woff,
              const float* __restrict__ Wa, const float* __restrict__ Wo,
              u16* __restrict__ qb, u16* __restrict__ ib,
              u16* __restrict__ wb) {
    const int b = blockIdx.x;
    const int t = threadIdx.x;
    if (b < 6647) {
        int i = b * 256 + t;
        float4 v = query[i];
        U16x4 o{f2bf(v.x), f2bf(v.y), f2bf(v.z), f2bf(v.w)};
        *(U16x4*)&qb[(size_t)i * 4] = o;
    } else if (b < 13294) {
        int i = (b - 6647) * 256 + t;
        float4 v = inflat[i];
        U16x4 o{f2bf(v.x), f2bf(v.y), f2bf(v.z), f2bf(v.w)};
        *(U16x4*)&ib[(size_t)i * 4] = o;
    } else {
        int i = (b - 13294) * 256 + t;      // 0..229375
        float v;
        if      (i <  65536) v = Wv[i];
        else if (i < 131072) v = Woff[i - 65536];
        else if (i < 163840) v = Wa[i - 131072];
        else                 v = Wo[i - 163840];
        wb[i] = f2bf(v);
    }
}

// ---------------------------------------------------------------------------
// Pipelined 64x128 GEMM core. B (128 cols x 256 k, 64 KB) staged into LDS
// ONCE in the prologue; A double-buffered (2 x 8 KB), staged one K-step
// ahead with counted s_waitcnt vmcnt(2) + raw barriers (loads stay in
// flight across the barrier — T3/T4). 16 MFMA per wave per K-step.
// ---------------------------------------------------------------------------
template<int KT>
__device__ __forceinline__ void kstep(
    const u16* __restrict__ A, int M, int row0, int tid,
    const u16* AsCur, u16* AsAlt, const u16* Bs,
    int wr, int wc, int ln16, int kq, f32x4 (&acc)[2][4]) {
    if constexpr (KT < 3) {
        const int k0n = (KT + 1) * 64;
        #pragma unroll
        for (int it = 0; it < 2; ++it) {
            int chunk = it * 256 + tid;         // 0..511
            int row = chunk >> 3, ch = chunk & 7;
            int chs = (ch ^ (row & 7)) * 8;
            int gra = min(row0 + row, M - 1);
            gload_lds16(A + (size_t)gra * 256 + k0n + chs, AsAlt + chunk * 8);
        }
        asm volatile("s_waitcnt vmcnt(2)" ::: "memory");  // A(KT) landed
    } else {
        asm volatile("s_waitcnt vmcnt(0)" ::: "memory");
    }
    block_barrier();                                       // all waves' A(KT) visible
    #pragma unroll
    for (int kf = 0; kf < 2; ++kf) {
        const int ck = kf * 4 + kq;             // 0..7  (A chunk in 64-k buf)
        const int gk = KT * 8 + ck;             // 0..31 (B chunk in 256-k)
        bf16x8 a[2], b[4];
        #pragma unroll
        for (int i = 0; i < 2; ++i) {
            int r = wr + i * 16 + ln16;
            a[i] = *(const bf16x8*)&AsCur[r * 64 + ((ck ^ (r & 7)) * 8)];
        }
        #pragma unroll
        for (int j = 0; j < 4; ++j) {
            int c = wc + j * 16 + ln16;
            int lch = (gk & 24) | ((gk & 7) ^ (c & 7));
            b[j] = *(const bf16x8*)&Bs[c * 256 + lch * 8];
        }
        #pragma unroll
        for (int i = 0; i < 2; ++i)
            #pragma unroll
            for (int j = 0; j < 4; ++j)
                acc[i][j] = __builtin_amdgcn_mfma_f32_16x16x32_bf16(
                    a[i], b[j], acc[i][j], 0, 0, 0);
    }
    block_barrier();                            // reads done -> AsAlt reusable
}

__device__ __forceinline__ void gemm_core_pipe(
    const u16* __restrict__ A, const u16* __restrict__ Bw, int M, int row0,
    u16* Bs, u16* As0, u16* As1, f32x4 (&acc)[2][4]) {
    const int tid  = threadIdx.x;
    const int lane = tid & 63;
    const int wave = tid >> 6;
    const int ln16 = lane & 15;
    const int kq   = lane >> 4;
    const int wr   = (wave >> 1) * 32;
    const int wc   = (wave & 1) * 64;

    // prologue: stage ALL of B (4096 chunks) + A(0) (512 chunks)
    #pragma unroll
    for (int it = 0; it < 16; ++it) {
        int cb = it * 256 + tid;                // 0..4095
        int row = cb >> 5, ch = cb & 31;
        int chs = (ch & 24) | ((ch & 7) ^ (row & 7));
        gload_lds16(Bw + (size_t)row * 256 + chs * 8, Bs + cb * 8);
    }
    #pragma unroll
    for (int it = 0; it < 2; ++it) {
        int chunk = it * 256 + tid;             // 0..511
        int row = chunk >> 3, ch = chunk & 7;
        int chs = (ch ^ (row & 7)) * 8;
        int gra = min(row0 + row, M - 1);
        gload_lds16(A + (size_t)gra * 256 + chs, As0 + chunk * 8);
    }
    asm volatile("s_waitcnt vmcnt(0)" ::: "memory");
    block_barrier();

    kstep<0>(A, M, row0, tid, As0, As1, Bs, wr, wc, ln16, kq, acc);
    kstep<1>(A, M, row0, tid, As1, As0, Bs, wr, wc, ln16, kq, acc);
    kstep<2>(A, M, row0, tid, As0, As1, Bs, wr, wc, ln16, kq, acc);
    kstep<3>(A, M, row0, tid, As1, As0, Bs, wr, wc, ln16, kq, acc);
}

// Front GEMMs (bf16 inputs via prep), BM=64 row tiles:
//   s=0,1 -> value = ib@Wv^T+bv   (bf16, HEAD-MAJOR [m][slice][32ch])
//   s=2,3 -> offb  = qb@Woff^T+boff (fp32)
//   s=4   -> logit = qb@Wa^T+ba     (fp32)
__global__ __launch_bounds__(256, 2)
void gemm_front(const u16* __restrict__ qb, const u16* __restrict__ ib,
                const u16* __restrict__ wb, const float* __restrict__ bv,
                const float* __restrict__ boff, const float* __restrict__ ba,
                u16* __restrict__ value, float* __restrict__ offb,
                float* __restrict__ logit, int M) {
    __shared__ u16 Sh[32768 + 8192];          // 80 KB: Bs(64K) | As0 | As1
    u16* Bs  = Sh;
    u16* As0 = Sh + 32768;
    u16* As1 = Sh + 32768 + 4096;
    const int s    = blockIdx.x;          // 0..4
    const int row0 = blockIdx.y * 64;
    const u16* A  = (s < 2) ? ib : qb;
    const u16* Bw = wb + (size_t)s * 32768;
    const float* bias = (s == 0) ? bv
                      : (s == 1) ? bv + 128
                      : (s == 2) ? boff
                      : (s == 3) ? boff + 128
                      : ba;

    f32x4 acc[2][4] = {};
    gemm_core_pipe(A, Bw, M, row0, Bs, As0, As1, acc);

    const int tid  = threadIdx.x;
    const int lane = tid & 63;
    const int wave = tid >> 6;
    const int ln16 = lane & 15, kq = lane >> 4;
    const int wr = (wave >> 1) * 32, wc = (wave & 1) * 64;

    if (s < 2) {
        // stage C tile (bf16) in LDS (Bs area is free now), then coalesced
        // 16B head-major stores
        #pragma unroll
        for (int j = 0; j < 4; ++j) {
            int cl = wc + j * 16 + ln16;
            float bj = bias[cl];
            #pragma unroll
            for (int i = 0; i < 2; ++i)
                #pragma unroll
                for (int r = 0; r < 4; ++r) {
                    int rl = wr + i * 16 + kq * 4 + r;
                    Sh[rl * 128 + cl] = f2bf(acc[i][j][r] + bj);
                }
        }
        __syncthreads();
        #pragma unroll
        for (int it = 0; it < 4; ++it) {
            int ci = it * 256 + tid;      // 0..1023
            int tr = ci >> 4;             // tile row 0..63
            int cc = ci & 15;             // 16B chunk (8 ch) within row
            int gr = row0 + tr;
            if (gr < M) {
                int cg = s * 128 + cc * 8;            // global channel base
                u16* dst = value + (size_t)(cg >> 5) * HS32
                                 + (size_t)gr * 32 + (cg & 31);
                *(uint4*)dst = *(const uint4*)&Sh[tr * 128 + cc * 8];
            }
        }
        // zero the pad slice of each head (read with weight 0 at the x edge)
        if (s == 0 && blockIdx.y == 0) {
            value[(size_t)(tid >> 5) * HS32 + (size_t)NROWS * 32 + (tid & 31)] = 0;
        }
    } else {
        #pragma unroll
        for (int j = 0; j < 4; ++j) {
            int lc = wc + j * 16 + ln16;  // 0..127 within strip
            float bj = bias[lc];
            #pragma unroll
            for (int i = 0; i < 2; ++i) {
                #pragma unroll
                for (int r = 0; r < 4; ++r) {
                    int gr = row0 + wr + i * 16 + kq * 4 + r;
                    if (gr < M) {
                        float o = acc[i][j][r] + bj;
                        if (s < 4)
                            offb[(size_t)gr * 256 + (s - 2) * 128 + lc] = o;
                        else
                            logit[(size_t)gr * 128 + lc] = o;
                    }
                }
            }
        }
    }
}

// out = tmp @ Wo^T + bo (fp32 out, ld 256), BM=64, strips 0..1 (128 cols)
__global__ __launch_bounds__(256, 2)
void gemm_out(const u16* __restrict__ A, const u16* __restrict__ Bw0,
              const float* __restrict__ bias, float* __restrict__ C, int M) {
    __shared__ u16 Sh[32768 + 8192];
    u16* Bs  = Sh;
    u16* As0 = Sh + 32768;
    u16* As1 = Sh + 32768 + 4096;
    const int s    = blockIdx.x;
    const int row0 = blockIdx.y * 64;
    const u16* Bw = Bw0 + (size_t)s * 32768;

    f32x4 acc[2][4] = {};
    gemm_core_pipe(A, Bw, M, row0, Bs, As0, As1, acc);

    const int lane = threadIdx.x & 63;
    const int wave = threadIdx.x >> 6;
    const int ln16 = lane & 15, kq = lane >> 4;
    const int wr = (wave >> 1) * 32, wc = (wave & 1) * 64;
    #pragma unroll
    for (int j = 0; j < 4; ++j) {
        int gc = s * 128 + wc + j * 16 + ln16;
        float bj = bias[gc];
        #pragma unroll
        for (int i = 0; i < 2; ++i) {
            #pragma unroll
            for (int r = 0; r < 4; ++r) {
                int gr = row0 + wr + i * 16 + kq * 4 + r;
                if (gr < M) C[(size_t)gr * 256 + gc] = acc[i][j][r] + bj;
            }
        }
    }
}

// Sampler: 4 queries/block. value is HEAD-MAJOR: corner pair (x0,x1) of one
// y-corner = one 128B segment loaded by 8 lanes x 16B. Phase C: 2-deep
// software pipeline with NAMED scalars (no arrays -> no scratch spill).
__global__ __launch_bounds__(256, 4)
void msda_sample(const u16* __restrict__ value,     // head-major bf16
                 const float* __restrict__ refpts,  // (NB*LQ, 4, 2)
                 const float* __restrict__ off,     // (NB*LQ, 256) fp32
                 const float* __restrict__ logits,  // (NB*LQ, 128) fp32
                 u16* __restrict__ tmp) {           // (NB*LQ, 256) bf16
    __shared__ float sAw[4][8][16];
    __shared__ int   sLin[4][8][17][2];   // pad 17: per-m bank shift of 2
    __shared__ float sW[4][8][17][4];     // pad 17: per-m bank shift of 4

    const int t  = threadIdx.x;
    const int qb = blockIdx.x * 4;

    // ---- Phase A: softmax per (q,m) ----
    if (t < 32) {
        const int qi = t >> 3, m = t & 7;
        const float* lg = logits + (size_t)(qb + qi) * 128 + m * 16;
        float e[16];
        float mx = -1e30f;
        #pragma unroll
        for (int i = 0; i < 16; ++i) { e[i] = lg[i]; mx = fmaxf(mx, e[i]); }
        float s = 0.f;
        #pragma unroll
        for (int i = 0; i < 16; ++i) { e[i] = __expf(e[i] - mx); s += e[i]; }
        const float inv = 1.f / s;
        #pragma unroll
        for (int i = 0; i < 16; ++i) sAw[qi][m][i] = e[i] * inv;
    }
    __syncthreads();

    // ---- Phase B: 512 point jobs, 2 per thread ----
    #pragma unroll
    for (int j2 = 0; j2 < 2; ++j2) {
        const int job = t + j2 * 256;
        const int qi = job >> 7;
        const int m  = (job >> 4) & 7;
        const int p  = job & 15;
        const int l  = p >> 2, pp = p & 3;
        const int q  = qb + qi;
        const int n  = (q >= LQ) ? 1 : 0;

        const int W = (l == 0) ? 100 : (l == 1) ? 50 : (l == 2) ? 25 : 13;
        const int H = W;
        const int st = (l == 0) ? 0 : (l == 1) ? 10000 : (l == 2) ? 12500 : 13125;
        const float invW = (l == 0) ? 0.01f : (l == 1) ? 0.02f
                         : (l == 2) ? 0.04f : (1.f / 13.f);

        const float rx = refpts[(size_t)q * 8 + l * 2 + 0];
        const float ry = refpts[(size_t)q * 8 + l * 2 + 1];
        const float ox = off[(size_t)q * 256 + m * 32 + (l * 4 + pp) * 2 + 0];
        const float oy = off[(size_t)q * 256 + m * 32 + (l * 4 + pp) * 2 + 1];

        const float locx = rx + ox * invW;
        const float locy = ry + oy * invW;
        const float grx = 2.f * locx - 1.f;
        const float gry = 2.f * locy - 1.f;
        const float gx = ((grx + 1.f) * (float)W - 1.f) * 0.5f;
        const float gy = ((gry + 1.f) * (float)H - 1.f) * 0.5f;
        const float x0f = floorf(gx), y0f = floorf(gy);
        const float fx = gx - x0f, fy = gy - y0f;
        const int x0 = (int)x0f, y0 = (int)y0f;
        const int x1 = x0 + 1, y1 = y0 + 1;

        const int cx0 = min(max(x0, 0), W - 1);
        const int cy0 = min(max(y0, 0), H - 1);
        const int cy1 = min(max(y1, 0), H - 1);
        const bool vx0 = (x0 >= 0) & (x0 < W);
        const bool vx1 = (x1 >= 0) & (x1 < W);
        const bool vy0 = (y0 >= 0) & (y0 < H);
        const bool vy1 = (y1 >= 0) & (y1 < H);

        const float aw = sAw[qi][m][p];
        const int base = n * LQ + st;
        const float w00 = (vy0 & vx0) ? aw * (1.f - fy) * (1.f - fx) : 0.f;
        const float w01 = (vy0 & vx1) ? aw * (1.f - fy) * fx         : 0.f;
        const float w10 = (vy1 & vx0) ? aw * fy * (1.f - fx)         : 0.f;
        const float w11 = (vy1 & vx1) ? aw * fy * fx                 : 0.f;
        // fold: when x0<0, corner x1 lives in the LOWER 64B (cx1==cx0==0);
        // w00 is exactly 0 there, so lo-slot gets w01 bit-identically.
        const bool fold = (x0 < 0);
        sLin[qi][m][p][0] = base + cy0 * W + cx0;
        sLin[qi][m][p][1] = base + cy1 * W + cx0;
        sW[qi][m][p][0] = fold ? w01 : w00;   // y0, lo half
        sW[qi][m][p][1] = fold ? 0.f : w01;   // y0, hi half
        sW[qi][m][p][2] = fold ? w11 : w10;   // y1, lo half
        sW[qi][m][p][3] = fold ? 0.f : w11;   // y1, hi half
    }
    __syncthreads();

    // ---- Phase C: t = [qi:2][m:3][xh:1][c4:2]. Per (q,m): 8 lanes.
    // Each p: two 128B pair-segments (y0,y1). 2-deep pipeline, named regs.
    const int qi = t >> 6;
    const int m  = (t >> 3) & 7;
    const int e  = t & 7;
    const int xh = e >> 2;                 // 0: x0 corner, 1: x1 corner
    const int c4 = e & 3;                  // 16B chunk within 64B slice
    const int q  = qb + qi;
    const char* vb = (const char*)value + (size_t)m * (HS32 * 2);
    const u32 eoff = (u32)e * 16u;

    f32x2 a2[4] = {{0.f, 0.f}, {0.f, 0.f}, {0.f, 0.f}, {0.f, 0.f}};

    int2   rbA = *(const int2*)  &sLin[qi][m][0][0];
    float4 w4A = *(const float4*)&sW  [qi][m][0][0];
    uint4  rA0 = *(const uint4*)(vb + ((u32)rbA.x * 64u + eoff));
    uint4  rA1 = *(const uint4*)(vb + ((u32)rbA.y * 64u + eoff));

    #pragma unroll
    for (int p = 0; p < 16; ++p) {
        int2   rbB; float4 w4B; uint4 rB0, rB1;
        if (p < 15) {
            rbB = *(const int2*)  &sLin[qi][m][p + 1][0];
            w4B = *(const float4*)&sW  [qi][m][p + 1][0];
            rB0 = *(const uint4*)(vb + ((u32)rbB.x * 64u + eoff));
            rB1 = *(const uint4*)(vb + ((u32)rbB.y * 64u + eoff));
        } else {
            rbB = rbA; w4B = w4A; rB0 = rA0; rB1 = rA1;
        }
        const float wa  = xh ? w4A.y : w4A.x;
        const float wb_ = xh ? w4A.w : w4A.z;
        f32x2 wa2 = {wa, wa};
        f32x2 wb2 = {wb_, wb_};
        a2[0] += wa2 * bfpair(rA0.x); a2[1] += wa2 * bfpair(rA0.y);
        a2[2] += wa2 * bfpair(rA0.z); a2[3] += wa2 * bfpair(rA0.w);
        a2[0] += wb2 * bfpair(rA1.x); a2[1] += wb2 * bfpair(rA1.y);
        a2[2] += wb2 * bfpair(rA1.z); a2[3] += wb2 * bfpair(rA1.w);
        rbA = rbB; w4A = w4B; rA0 = rB0; rA1 = rB1;
    }
    // combine x0/x1 halves (partner lane differs in bit 2)
    #pragma unroll
    for (int k = 0; k < 4; ++k) {
        a2[k].x += __shfl_xor(a2[k].x, 4);
        a2[k].y += __shfl_xor(a2[k].y, 4);
    }
    if (xh == 0) {
        uint4 o;
        o.x = (u32)f2bf(a2[0].x) | ((u32)f2bf(a2[0].y) << 16);
        o.y = (u32)f2bf(a2[1].x) | ((u32)f2bf(a2[1].y) << 16);
        o.z = (u32)f2bf(a2[2].x) | ((u32)f2bf(a2[2].y) << 16);
        o.w = (u32)f2bf(a2[3].x) | ((u32)f2bf(a2[3].y) << 16);
        *(uint4*)((char*)tmp + ((u32)q * 512u + (u32)m * 64u + (u32)c4 * 16u)) = o;
    }
}

extern "C" void kernel_launch(void* const* d_in, const int* in_sizes, int n_in,
                              void* d_out, int out_size, void* d_ws, size_t ws_size,
                              hipStream_t stream) {
    const float* query  = (const float*)d_in[0];
    const float* refpts = (const float*)d_in[1];
    const float* inflat = (const float*)d_in[2];
    const float* Wv   = (const float*)d_in[5];
    const float* bv   = (const float*)d_in[6];
    const float* Woff = (const float*)d_in[7];
    const float* boff = (const float*)d_in[8];
    const float* Wa   = (const float*)d_in[9];
    const float* ba   = (const float*)d_in[10];
    const float* Wo   = (const float*)d_in[11];
    const float* bo   = (const float*)d_in[12];
    float* out = (float*)d_out;

    // workspace layout (~82 MB)
    char* ws = (char*)d_ws;
    constexpr size_t SZ16  = (size_t)NROWS * 256 * 2;          // 13,613,056
    constexpr size_t SZVAL = ((size_t)HSLICES * 512 + 4095) & ~(size_t)4095;
    constexpr size_t SZ32  = (size_t)NROWS * 256 * 4;          // 27,226,112
    constexpr size_t SZL   = (size_t)NROWS * 128 * 4;          // 13,613,056
    u16*   qb    = (u16*)(ws);                                 // bf16 query; later tmp
    u16*   ib    = (u16*)(ws + SZ16);                          // bf16 input
    u16*   value = (u16*)(ws + 2 * SZ16);                      // bf16 head-major
    float* offb  = (float*)(ws + 2 * SZ16 + SZVAL);            // fp32
    float* logit = (float*)(ws + 2 * SZ16 + SZVAL + SZ32);     // fp32
    u16*   wb    = (u16*)(ws + 2 * SZ16 + SZVAL + SZ32 + SZL); // bf16 weights
    u16*   tmp   = qb;

    const int RG = (NROWS + 63) / 64;   // 416 row-groups (BM=64)

    hipLaunchKernelGGL(prep_all, dim3(14190), dim3(256), 0, stream,
                       (const float4*)query, (const float4*)inflat,
                       Wv, Woff, Wa, Wo, qb, ib, wb);

    gemm_front<<<dim3(5, RG), dim3(256), 0, stream>>>(
        qb, ib, wb, bv, boff, ba, value, offb, logit, NROWS);

    hipLaunchKernelGGL(msda_sample, dim3(NROWS / 4), dim3(256), 0, stream,
                       value, refpts, offb, logit, tmp);

    gemm_out<<<dim3(2, RG), dim3(256), 0, stream>>>(
        tmp, wb + 163840, bo, out, NROWS);
}

// Round 9
// 199.719 us; speedup vs baseline: 1.0822x; 1.0822x over previous
//
#include <hip/hip_runtime.h>
#include <math.h>

// Problem constants (compile-time fixed)
#define NB   2
#define LQ   13294
#define NROWS (NB*LQ)      // 26588
#define CDIM 256
#define HSLICES (NROWS + 1)                       // +1 zero pad slice per head
#define HS32 ((size_t)HSLICES * 32)               // u16 per head

typedef unsigned short u16;
typedef unsigned int   u32;
typedef short bf16x8 __attribute__((ext_vector_type(8)));
typedef float f32x4  __attribute__((ext_vector_type(4)));
typedef float f32x2  __attribute__((ext_vector_type(2)));

struct alignas(8) U16x4 { u16 x, y, z, w; };

__device__ __forceinline__ u16 f2bf(float f) {   // round-to-nearest-even
    u32 u = __builtin_bit_cast(u32, f);
    u += 0x7FFFu + ((u >> 16) & 1u);
    return (u16)(u >> 16);
}

__device__ __forceinline__ void gload_lds16(const void* g, void* l) {
    __builtin_amdgcn_global_load_lds(
        (__attribute__((address_space(1))) void*)g,
        (__attribute__((address_space(3))) void*)l, 16, 0, 0);
}

// unpack one u32 of 2 packed bf16 into f32x2 {lo, hi}
__device__ __forceinline__ f32x2 bfpair(u32 u) {
    union { u32 w[2]; f32x2 v; } x;
    x.w[0] = u << 16;
    x.w[1] = u & 0xFFFF0000u;
    return x.v;
}

// ONE prep dispatch: cvt query (blocks 0..6646), cvt inflat (6647..13293),
// weights concat [Wv|Woff|Wa|Wo] -> bf16 (13294..14189).
__global__ __launch_bounds__(256)
void prep_all(const float4* __restrict__ query, const float4* __restrict__ inflat,
              const float* __restrict__ Wv, const float* __restrict__ Woff,
              const float* __restrict__ Wa, const float* __restrict__ Wo,
              u16* __restrict__ qb, u16* __restrict__ ib,
              u16* __restrict__ wb) {
    const int b = blockIdx.x;
    const int t = threadIdx.x;
    if (b < 6647) {
        int i = b * 256 + t;
        float4 v = query[i];
        U16x4 o{f2bf(v.x), f2bf(v.y), f2bf(v.z), f2bf(v.w)};
        *(U16x4*)&qb[(size_t)i * 4] = o;
    } else if (b < 13294) {
        int i = (b - 6647) * 256 + t;
        float4 v = inflat[i];
        U16x4 o{f2bf(v.x), f2bf(v.y), f2bf(v.z), f2bf(v.w)};
        *(U16x4*)&ib[(size_t)i * 4] = o;
    } else {
        int i = (b - 13294) * 256 + t;      // 0..229375
        float v;
        if      (i <  65536) v = Wv[i];
        else if (i < 131072) v = Woff[i - 65536];
        else if (i < 163840) v = Wa[i - 131072];
        else                 v = Wo[i - 163840];
        wb[i] = f2bf(v);
    }
}

// 64x128 GEMM core: BM=64 rows, BN=128 cols, BK=64, 4 K-iters, 24 KB LDS,
// global_load_lds width-16 staging (linear LDS dest + pre-swizzled source).
// 4 waves; wave w owns 32x64 quadrant ((w>>1)*32, (w&1)*64) as acc[2][4].
__device__ __forceinline__ void gemm_core64(
    const u16* __restrict__ A, const u16* __restrict__ Bw, int M, int row0,
    u16* As, u16* Bs, f32x4 (&acc)[2][4]) {
    const int tid  = threadIdx.x;
    const int lane = tid & 63;
    const int wave = tid >> 6;
    const int ln16 = lane & 15;
    const int kq   = lane >> 4;
    const int wr   = (wave >> 1) * 32;
    const int wc   = (wave & 1) * 64;

    #pragma unroll
    for (int kt = 0; kt < 4; ++kt) {
        const int k0 = kt * 64;
        // A: 512 chunks (64 rows x 8), B: 1024 chunks (128 rows x 8)
        #pragma unroll
        for (int it = 0; it < 2; ++it) {
            int chunk = it * 256 + tid;         // 0..511
            int row = chunk >> 3, ch = chunk & 7;
            int chs = (ch ^ (row & 7)) * 8;
            int gra = min(row0 + row, M - 1);
            gload_lds16(A + (size_t)gra * 256 + k0 + chs, As + chunk * 8);
        }
        #pragma unroll
        for (int it = 0; it < 4; ++it) {
            int cb = it * 256 + tid;            // 0..1023
            int row = cb >> 3, ch = cb & 7;
            int chs = (ch ^ (row & 7)) * 8;
            gload_lds16(Bw + (size_t)row * 256 + k0 + chs, Bs + cb * 8);
        }
        __syncthreads();
        #pragma unroll
        for (int kf = 0; kf < 2; ++kf) {
            const int ck = kf * 4 + kq;
            bf16x8 a[2], b[4];
            #pragma unroll
            for (int i = 0; i < 2; ++i) {
                int r = wr + i * 16 + ln16;
                a[i] = *(const bf16x8*)&As[r * 64 + ((ck ^ (r & 7)) * 8)];
            }
            #pragma unroll
            for (int j = 0; j < 4; ++j) {
                int c = wc + j * 16 + ln16;
                b[j] = *(const bf16x8*)&Bs[c * 64 + ((ck ^ (c & 7)) * 8)];
            }
            #pragma unroll
            for (int i = 0; i < 2; ++i)
                #pragma unroll
                for (int j = 0; j < 4; ++j)
                    acc[i][j] = __builtin_amdgcn_mfma_f32_16x16x32_bf16(
                        a[i], b[j], acc[i][j], 0, 0, 0);
        }
        __syncthreads();
    }
}

// Front GEMMs (bf16 inputs via prep), BM=64 row tiles, 1-D grid of 2080
// blocks with XCD-aware remap: all 5 strips of a rowgroup land on the SAME
// XCD (xcd = lid&7 owns rowgroups [xcd*52, xcd*52+52)) so A-rows are
// fetched once into that XCD's L2 and the other strips hit L2.
//   s=0,1 -> value = ib@Wv^T+bv   (bf16, HEAD-MAJOR [m][slice][32ch])
//   s=2,3 -> offb  = qb@Woff^T+boff (fp32)
//   s=4   -> logit = qb@Wa^T+ba     (fp32)
__global__ __launch_bounds__(256, 4)
void gemm_front(const u16* __restrict__ qb, const u16* __restrict__ ib,
                const u16* __restrict__ wb, const float* __restrict__ bv,
                const float* __restrict__ boff, const float* __restrict__ ba,
                u16* __restrict__ value, float* __restrict__ offb,
                float* __restrict__ logit, int M) {
    __shared__ u16 Sh[64 * 64 + 128 * 64];   // 24 KB: As | Bs
    u16* As = Sh;
    u16* Bs = Sh + 4096;
    const int lid  = blockIdx.x;          // 0..2079  (2080 = 8*52*5)
    const int xcd  = lid & 7;
    const int idx  = lid >> 3;            // 0..259
    const int rg   = xcd * 52 + idx / 5;  // 0..415
    const int s    = idx % 5;             // 0..4
    const int row0 = rg * 64;
    const u16* A  = (s < 2) ? ib : qb;
    const u16* Bw = wb + (size_t)s * 32768;
    const float* bias = (s == 0) ? bv
                      : (s == 1) ? bv + 128
                      : (s == 2) ? boff
                      : (s == 3) ? boff + 128
                      : ba;

    f32x4 acc[2][4] = {};
    gemm_core64(A, Bw, M, row0, As, Bs, acc);

    const int tid  = threadIdx.x;
    const int lane = tid & 63;
    const int wave = tid >> 6;
    const int ln16 = lane & 15, kq = lane >> 4;
    const int wr = (wave >> 1) * 32, wc = (wave & 1) * 64;

    if (s < 2) {
        // stage C tile (bf16) in LDS, then coalesced 16B head-major stores
        #pragma unroll
        for (int j = 0; j < 4; ++j) {
            int cl = wc + j * 16 + ln16;
            float bj = bias[cl];
            #pragma unroll
            for (int i = 0; i < 2; ++i)
                #pragma unroll
                for (int r = 0; r < 4; ++r) {
                    int rl = wr + i * 16 + kq * 4 + r;
                    Sh[rl * 128 + cl] = f2bf(acc[i][j][r] + bj);
                }
        }
        __syncthreads();
        #pragma unroll
        for (int it = 0; it < 4; ++it) {
            int ci = it * 256 + tid;      // 0..1023
            int tr = ci >> 4;             // tile row 0..63
            int cc = ci & 15;             // 16B chunk (8 ch) within row
            int gr = row0 + tr;
            if (gr < M) {
                int cg = s * 128 + cc * 8;            // global channel base
                u16* dst = value + (size_t)(cg >> 5) * HS32
                                 + (size_t)gr * 32 + (cg & 31);
                *(uint4*)dst = *(const uint4*)&Sh[tr * 128 + cc * 8];
            }
        }
        // zero the pad slice of each head (read with weight 0 at the x edge)
        if (s == 0 && rg == 0) {
            value[(size_t)(tid >> 5) * HS32 + (size_t)NROWS * 32 + (tid & 31)] = 0;
        }
    } else {
        #pragma unroll
        for (int j = 0; j < 4; ++j) {
            int lc = wc + j * 16 + ln16;  // 0..127 within strip
            float bj = bias[lc];
            #pragma unroll
            for (int i = 0; i < 2; ++i) {
                #pragma unroll
                for (int r = 0; r < 4; ++r) {
                    int gr = row0 + wr + i * 16 + kq * 4 + r;
                    if (gr < M) {
                        float o = acc[i][j][r] + bj;
                        if (s < 4)
                            offb[(size_t)gr * 256 + (s - 2) * 128 + lc] = o;
                        else
                            logit[(size_t)gr * 128 + lc] = o;
                    }
                }
            }
        }
    }
}

// out = tmp @ Wo^T + bo (fp32 out, ld 256), BM=64, 1-D grid of 832 blocks
// (8*52*2) with the same XCD-aware remap (2 strips of a rowgroup share an
// XCD so the A (tmp) rows are fetched once).
__global__ __launch_bounds__(256, 4)
void gemm_out(const u16* __restrict__ A, const u16* __restrict__ Bw0,
              const float* __restrict__ bias, float* __restrict__ C, int M) {
    __shared__ u16 Sh[64 * 64 + 128 * 64];
    u16* As = Sh;
    u16* Bs = Sh + 4096;
    const int lid  = blockIdx.x;          // 0..831
    const int xcd  = lid & 7;
    const int idx  = lid >> 3;            // 0..103
    const int rg   = xcd * 52 + idx / 2;  // 0..415
    const int s    = idx % 2;
    const int row0 = rg * 64;
    const u16* Bw = Bw0 + (size_t)s * 32768;

    f32x4 acc[2][4] = {};
    gemm_core64(A, Bw, M, row0, As, Bs, acc);

    const int lane = threadIdx.x & 63;
    const int wave = threadIdx.x >> 6;
    const int ln16 = lane & 15, kq = lane >> 4;
    const int wr = (wave >> 1) * 32, wc = (wave & 1) * 64;
    #pragma unroll
    for (int j = 0; j < 4; ++j) {
        int gc = s * 128 + wc + j * 16 + ln16;
        float bj = bias[gc];
        #pragma unroll
        for (int i = 0; i < 2; ++i) {
            #pragma unroll
            for (int r = 0; r < 4; ++r) {
                int gr = row0 + wr + i * 16 + kq * 4 + r;
                if (gr < M) C[(size_t)gr * 256 + gc] = acc[i][j][r] + bj;
            }
        }
    }
}

// Sampler: 4 queries/block. value is HEAD-MAJOR: corner pair (x0,x1) of one
// y-corner = one 128B segment loaded by 8 lanes x 16B. Phase C: 2-deep
// software pipeline with NAMED scalars (no arrays -> no scratch spill).
__global__ __launch_bounds__(256, 4)
void msda_sample(const u16* __restrict__ value,     // head-major bf16
                 const float* __restrict__ refpts,  // (NB*LQ, 4, 2)
                 const float* __restrict__ off,     // (NB*LQ, 256) fp32
                 const float* __restrict__ logits,  // (NB*LQ, 128) fp32
                 u16* __restrict__ tmp) {           // (NB*LQ, 256) bf16
    __shared__ float sAw[4][8][16];
    __shared__ int   sLin[4][8][17][2];   // pad 17: per-m bank shift of 2
    __shared__ float sW[4][8][17][4];     // pad 17: per-m bank shift of 4

    const int t  = threadIdx.x;
    const int qb = blockIdx.x * 4;

    // ---- Phase A: softmax per (q,m) ----
    if (t < 32) {
        const int qi = t >> 3, m = t & 7;
        const float* lg = logits + (size_t)(qb + qi) * 128 + m * 16;
        float e[16];
        float mx = -1e30f;
        #pragma unroll
        for (int i = 0; i < 16; ++i) { e[i] = lg[i]; mx = fmaxf(mx, e[i]); }
        float s = 0.f;
        #pragma unroll
        for (int i = 0; i < 16; ++i) { e[i] = __expf(e[i] - mx); s += e[i]; }
        const float inv = 1.f / s;
        #pragma unroll
        for (int i = 0; i < 16; ++i) sAw[qi][m][i] = e[i] * inv;
    }
    __syncthreads();

    // ---- Phase B: 512 point jobs, 2 per thread ----
    #pragma unroll
    for (int j2 = 0; j2 < 2; ++j2) {
        const int job = t + j2 * 256;
        const int qi = job >> 7;
        const int m  = (job >> 4) & 7;
        const int p  = job & 15;
        const int l  = p >> 2, pp = p & 3;
        const int q  = qb + qi;
        const int n  = (q >= LQ) ? 1 : 0;

        const int W = (l == 0) ? 100 : (l == 1) ? 50 : (l == 2) ? 25 : 13;
        const int H = W;
        const int st = (l == 0) ? 0 : (l == 1) ? 10000 : (l == 2) ? 12500 : 13125;
        const float invW = (l == 0) ? 0.01f : (l == 1) ? 0.02f
                         : (l == 2) ? 0.04f : (1.f / 13.f);

        const float rx = refpts[(size_t)q * 8 + l * 2 + 0];
        const float ry = refpts[(size_t)q * 8 + l * 2 + 1];
        const float ox = off[(size_t)q * 256 + m * 32 + (l * 4 + pp) * 2 + 0];
        const float oy = off[(size_t)q * 256 + m * 32 + (l * 4 + pp) * 2 + 1];

        const float locx = rx + ox * invW;
        const float locy = ry + oy * invW;
        const float grx = 2.f * locx - 1.f;
        const float gry = 2.f * locy - 1.f;
        const float gx = ((grx + 1.f) * (float)W - 1.f) * 0.5f;
        const float gy = ((gry + 1.f) * (float)H - 1.f) * 0.5f;
        const float x0f = floorf(gx), y0f = floorf(gy);
        const float fx = gx - x0f, fy = gy - y0f;
        const int x0 = (int)x0f, y0 = (int)y0f;
        const int x1 = x0 + 1, y1 = y0 + 1;

        const int cx0 = min(max(x0, 0), W - 1);
        const int cy0 = min(max(y0, 0), H - 1);
        const int cy1 = min(max(y1, 0), H - 1);
        const bool vx0 = (x0 >= 0) & (x0 < W);
        const bool vx1 = (x1 >= 0) & (x1 < W);
        const bool vy0 = (y0 >= 0) & (y0 < H);
        const bool vy1 = (y1 >= 0) & (y1 < H);

        const float aw = sAw[qi][m][p];
        const int base = n * LQ + st;
        const float w00 = (vy0 & vx0) ? aw * (1.f - fy) * (1.f - fx) : 0.f;
        const float w01 = (vy0 & vx1) ? aw * (1.f - fy) * fx         : 0.f;
        const float w10 = (vy1 & vx0) ? aw * fy * (1.f - fx)         : 0.f;
        const float w11 = (vy1 & vx1) ? aw * fy * fx                 : 0.f;
        // fold: when x0<0, corner x1 lives in the LOWER 64B (cx1==cx0==0);
        // w00 is exactly 0 there, so lo-slot gets w01 bit-identically.
        const bool fold = (x0 < 0);
        sLin[qi][m][p][0] = base + cy0 * W + cx0;
        sLin[qi][m][p][1] = base + cy1 * W + cx0;
        sW[qi][m][p][0] = fold ? w01 : w00;   // y0, lo half
        sW[qi][m][p][1] = fold ? 0.f : w01;   // y0, hi half
        sW[qi][m][p][2] = fold ? w11 : w10;   // y1, lo half
        sW[qi][m][p][3] = fold ? 0.f : w11;   // y1, hi half
    }
    __syncthreads();

    // ---- Phase C: t = [qi:2][m:3][xh:1][c4:2]. Per (q,m): 8 lanes.
    // Each p: two 128B pair-segments (y0,y1). 2-deep pipeline, named regs.
    const int qi = t >> 6;
    const int m  = (t >> 3) & 7;
    const int e  = t & 7;
    const int xh = e >> 2;                 // 0: x0 corner, 1: x1 corner
    const int c4 = e & 3;                  // 16B chunk within 64B slice
    const int q  = qb + qi;
    const char* vb = (const char*)value + (size_t)m * (HS32 * 2);
    const u32 eoff = (u32)e * 16u;

    f32x2 a2[4] = {{0.f, 0.f}, {0.f, 0.f}, {0.f, 0.f}, {0.f, 0.f}};

    int2   rbA = *(const int2*)  &sLin[qi][m][0][0];
    float4 w4A = *(const float4*)&sW  [qi][m][0][0];
    uint4  rA0 = *(const uint4*)(vb + ((u32)rbA.x * 64u + eoff));
    uint4  rA1 = *(const uint4*)(vb + ((u32)rbA.y * 64u + eoff));

    #pragma unroll
    for (int p = 0; p < 16; ++p) {
        int2   rbB; float4 w4B; uint4 rB0, rB1;
        if (p < 15) {
            rbB = *(const int2*)  &sLin[qi][m][p + 1][0];
            w4B = *(const float4*)&sW  [qi][m][p + 1][0];
            rB0 = *(const uint4*)(vb + ((u32)rbB.x * 64u + eoff));
            rB1 = *(const uint4*)(vb + ((u32)rbB.y * 64u + eoff));
        } else {
            rbB = rbA; w4B = w4A; rB0 = rA0; rB1 = rA1;
        }
        const float wa  = xh ? w4A.y : w4A.x;
        const float wb_ = xh ? w4A.w : w4A.z;
        f32x2 wa2 = {wa, wa};
        f32x2 wb2 = {wb_, wb_};
        a2[0] += wa2 * bfpair(rA0.x); a2[1] += wa2 * bfpair(rA0.y);
        a2[2] += wa2 * bfpair(rA0.z); a2[3] += wa2 * bfpair(rA0.w);
        a2[0] += wb2 * bfpair(rA1.x); a2[1] += wb2 * bfpair(rA1.y);
        a2[2] += wb2 * bfpair(rA1.z); a2[3] += wb2 * bfpair(rA1.w);
        rbA = rbB; w4A = w4B; rA0 = rB0; rA1 = rB1;
    }
    // combine x0/x1 halves (partner lane differs in bit 2)
    #pragma unroll
    for (int k = 0; k < 4; ++k) {
        a2[k].x += __shfl_xor(a2[k].x, 4);
        a2[k].y += __shfl_xor(a2[k].y, 4);
    }
    if (xh == 0) {
        uint4 o;
        o.x = (u32)f2bf(a2[0].x) | ((u32)f2bf(a2[0].y) << 16);
        o.y = (u32)f2bf(a2[1].x) | ((u32)f2bf(a2[1].y) << 16);
        o.z = (u32)f2bf(a2[2].x) | ((u32)f2bf(a2[2].y) << 16);
        o.w = (u32)f2bf(a2[3].x) | ((u32)f2bf(a2[3].y) << 16);
        *(uint4*)((char*)tmp + ((u32)q * 512u + (u32)m * 64u + (u32)c4 * 16u)) = o;
    }
}

extern "C" void kernel_launch(void* const* d_in, const int* in_sizes, int n_in,
                              void* d_out, int out_size, void* d_ws, size_t ws_size,
                              hipStream_t stream) {
    const float* query  = (const float*)d_in[0];
    const float* refpts = (const float*)d_in[1];
    const float* inflat = (const float*)d_in[2];
    const float* Wv   = (const float*)d_in[5];
    const float* bv   = (const float*)d_in[6];
    const float* Woff = (const float*)d_in[7];
    const float* boff = (const float*)d_in[8];
    const float* Wa   = (const float*)d_in[9];
    const float* ba   = (const float*)d_in[10];
    const float* Wo   = (const float*)d_in[11];
    const float* bo   = (const float*)d_in[12];
    float* out = (float*)d_out;

    // workspace layout (~82 MB)
    char* ws = (char*)d_ws;
    constexpr size_t SZ16  = (size_t)NROWS * 256 * 2;          // 13,613,056
    constexpr size_t SZVAL = ((size_t)HSLICES * 512 + 4095) & ~(size_t)4095;
    constexpr size_t SZ32  = (size_t)NROWS * 256 * 4;          // 27,226,112
    constexpr size_t SZL   = (size_t)NROWS * 128 * 4;          // 13,613,056
    u16*   qb    = (u16*)(ws);                                 // bf16 query; later tmp
    u16*   ib    = (u16*)(ws + SZ16);                          // bf16 input
    u16*   value = (u16*)(ws + 2 * SZ16);                      // bf16 head-major
    float* offb  = (float*)(ws + 2 * SZ16 + SZVAL);            // fp32
    float* logit = (float*)(ws + 2 * SZ16 + SZVAL + SZ32);     // fp32
    u16*   wb    = (u16*)(ws + 2 * SZ16 + SZVAL + SZ32 + SZL); // bf16 weights
    u16*   tmp   = qb;

    hipLaunchKernelGGL(prep_all, dim3(14190), dim3(256), 0, stream,
                       (const float4*)query, (const float4*)inflat,
                       Wv, Woff, Wa, Wo, qb, ib, wb);

    gemm_front<<<dim3(2080), dim3(256), 0, stream>>>(
        qb, ib, wb, bv, boff, ba, value, offb, logit, NROWS);

    hipLaunchKernelGGL(msda_sample, dim3(NROWS / 4), dim3(256), 0, stream,
                       value, refpts, offb, logit, tmp);

    gemm_out<<<dim3(832), dim3(256), 0, stream>>>(
        tmp, wb + 163840, bo, out, NROWS);
}